// Round 4
// baseline (1567.353 us; speedup 1.0000x reference)
//
#include <hip/hip_runtime.h>
#include <cstdint>

#define DIMD 256
#define KCB  4096
#define NQ   4
#define NTOK 32768   // 8 * 4096
#define BN   128     // cols per block (persistent B in LDS)
#define RPB  4096    // rows per block (NTOK / 8 row groups)
#define RT   512     // rows per iteration (8 waves x 64)

typedef __attribute__((ext_vector_type(8))) _Float16 half8;
typedef __attribute__((ext_vector_type(4))) _Float16 half4;
typedef __attribute__((ext_vector_type(4))) float f32x4;

// ---------------------------------------------------------------- helpers
__device__ __forceinline__ void async16(const void* g, void* l) {
  __builtin_amdgcn_global_load_lds(
      (const __attribute__((address_space(1))) unsigned int*)g,
      (__attribute__((address_space(3))) unsigned int*)l, 16, 0, 0);
}

__device__ __forceinline__ f32x4 mfma16(half8 a, half8 b, f32x4 c) {
  return __builtin_amdgcn_mfma_f32_16x16x32_f16(a, b, c, 0, 0, 0);
}

// ---------------------------------------------------------------- prep
// A plane pre-tiled frag-linear for mfma_f32_16x16x32 A-operand:
// half index = ((kc*(NTOK/16) + rowBlock16)*64 + (q*16 + (row&15)))*8 + j
// where element (row, d): kc=d>>5, q=(d>>3)&3, j=d&7.
__global__ void init_kernel(const float* __restrict__ x,
                            float* __restrict__ res,
                            _Float16* __restrict__ At) {
  const int tid = threadIdx.x;
  const int n = blockIdx.x * 8 + (tid >> 5);
  const int t = tid & 31;
  const size_t base = (size_t)n * DIMD + t * 8;
  const float4 v0 = *(const float4*)&x[base];
  const float4 v1 = *(const float4*)&x[base + 4];
  *(float4*)&res[base]     = v0;
  *(float4*)&res[base + 4] = v1;
  const float f[8] = {v0.x, v0.y, v0.z, v0.w, v1.x, v1.y, v1.z, v1.w};
  half8 h;
  #pragma unroll
  for (int j = 0; j < 8; ++j) h[j] = (_Float16)f[j];
  const int kc = t >> 2, q = t & 3;
  *(half8*)&At[(((size_t)(kc * (NTOK / 16) + (n >> 4))) * 64 + q * 16 + (n & 15)) * 8] = h;
}

__global__ void cb_prep_kernel(const float* __restrict__ cbs,
                               _Float16* __restrict__ Bt,
                               float* __restrict__ cn) {
  const int tid = threadIdx.x;
  const int R = blockIdx.x * 8 + (tid >> 5);   // layer*4096 + code
  const int layer = R >> 12, c = R & 4095;
  const int t = tid & 31;
  const size_t base = (size_t)R * DIMD + t * 8;
  const float4 v0 = *(const float4*)&cbs[base];
  const float4 v1 = *(const float4*)&cbs[base + 4];
  const float f[8] = {v0.x, v0.y, v0.z, v0.w, v1.x, v1.y, v1.z, v1.w};
  half8 h;
  float s = 0.f;
  #pragma unroll
  for (int j = 0; j < 8; ++j) { h[j] = (_Float16)f[j]; s += f[j] * f[j]; }
  const int kc = t >> 2, q = t & 3;
  _Float16* BtL = Bt + (size_t)layer * KCB * DIMD;
  *(half8*)&BtL[(((size_t)(kc * (KCB / 16) + (c >> 4))) * 64 + q * 16 + (c & 15)) * 8] = h;
  #pragma unroll
  for (int off = 16; off > 0; off >>= 1) s += __shfl_down(s, off, 32);
  if (t == 0) cn[R] = s;
}

// ---------------------------------------------------------------- argmin
// Persistent B (128 cols x 256 dims fp16 = 64 KB LDS), A direct global->VGPR.
// XCD swizzle: rowGroup = blockIdx & 7 so all 32 col-tiles of one row group
// share one XCD -> the 2 MB A slice stays L2-resident (was the R3 bottleneck:
// colTile-major put all 8 groups on every XCD, 16 MB > 4 MiB L2, 581 MB L3).
__global__ __launch_bounds__(512, 2) void argmin_kernel(
    const _Float16* __restrict__ At,
    const _Float16* __restrict__ Bt,     // layer base
    const float* __restrict__ cn,        // layer base
    float4* __restrict__ part)           // [32][NTOK] (v1,i1,v2,i2)
{
  __shared__ _Float16 Bs[BN * DIMD];     // frag id = kc*8+f at id*512 halfs

  const int tid = threadIdx.x;
  const int lane = tid & 63, w = tid >> 6;
  const int colTile = blockIdx.x >> 3;   // 0..31
  const int g = blockIdx.x & 7;          // row group 0..7 == XCD id
  const int colBase = colTile * BN;
  const int quad = lane >> 4, ln = lane & 15;

  // stage B once (8 x 1KB fragments per wave)
  #pragma unroll
  for (int s = 0; s < 8; ++s) {
    const int id = w * 8 + s;            // kc = id>>3, f = id&7
    const int kc = id >> 3, f = id & 7;
    const size_t goff = (((size_t)(kc * (KCB / 16) + colTile * 8 + f)) * 64 + lane) * 16;
    async16((const char*)Bt + goff, (char*)Bs + (size_t)id * 1024);
  }
  float cnv[8];
  #pragma unroll
  for (int j = 0; j < 8; ++j) cnv[j] = cn[colBase + j * 16 + ln];
  __syncthreads();   // the only barrier

  int rb = g * (RPB / 16) + w * 4;       // rowBlock16 base at rt=0
  half8 a_cur[4];
  #pragma unroll
  for (int i = 0; i < 4; ++i)
    a_cur[i] = *(const half8*)&At[(((size_t)(rb + i)) * 64 + lane) * 8];  // kc=0

  for (int rt = 0; rt < RPB / RT; ++rt) {
    f32x4 acc[4][8];
    #pragma unroll
    for (int i = 0; i < 4; ++i)
      #pragma unroll
      for (int j = 0; j < 8; ++j) acc[i][j] = (f32x4){0.f, 0.f, 0.f, 0.f};

    #pragma unroll
    for (int kc = 0; kc < 8; ++kc) {
      // prefetch next (kc+1, or next rt kc=0; wraps harmlessly on last)
      int nkc = kc + 1, nrb = rb;
      if (nkc == 8) { nkc = 0; nrb = (rt == RPB / RT - 1) ? g * (RPB / 16) + w * 4 : rb + 32; }
      half8 a_nxt[4];
      #pragma unroll
      for (int i = 0; i < 4; ++i)
        a_nxt[i] = *(const half8*)&At[(((size_t)(nkc * (NTOK / 16) + nrb + i)) * 64 + lane) * 8];

      #pragma unroll
      for (int j = 0; j < 8; ++j) {
        const half8 b = *(const half8*)&Bs[((size_t)(kc * 8 + j)) * 512 + lane * 8];
        acc[0][j] = mfma16(a_cur[0], b, acc[0][j]);
        acc[1][j] = mfma16(a_cur[1], b, acc[1][j]);
        acc[2][j] = mfma16(a_cur[2], b, acc[2][j]);
        acc[3][j] = mfma16(a_cur[3], b, acc[3][j]);
      }
      #pragma unroll
      for (int i = 0; i < 4; ++i) a_cur[i] = a_nxt[i];
    }

    // epilogue: best-2 per row over this block's 128 cols (no tie-break
    // needed — global top-8 fp64 rescore is the arbiter)
    #pragma unroll
    for (int i = 0; i < 4; ++i) {
      #pragma unroll
      for (int reg = 0; reg < 4; ++reg) {
        float v1 = 3.0e38f, v2 = 3.0e38f; int i1 = colBase, i2 = colBase + 1;
        #pragma unroll
        for (int j = 0; j < 8; ++j) {
          const float d = cnv[j] - 2.0f * acc[i][j][reg];
          const int c = colBase + j * 16 + ln;
          if (d < v1) { v2 = v1; i2 = i1; v1 = d; i1 = c; }
          else if (d < v2) { v2 = d; i2 = c; }
        }
        #pragma unroll
        for (int m = 1; m <= 8; m <<= 1) {
          const float u1 = __shfl_xor(v1, m, 64); const int j1 = __shfl_xor(i1, m, 64);
          const float u2 = __shfl_xor(v2, m, 64); const int j2 = __shfl_xor(i2, m, 64);
          if (u1 < v1) {
            v2 = (u2 < v1) ? u2 : v1; i2 = (u2 < v1) ? j2 : i1;
            v1 = u1; i1 = j1;
          } else if (u1 < v2) { v2 = u1; i2 = j1; }
        }
        if (ln == 0) {
          const int rowg = g * RPB + rt * RT + w * 64 + i * 16 + quad * 4 + reg;
          part[(size_t)colTile * NTOK + rowg] =
              make_float4(v1, __int_as_float(i1), v2, __int_as_float(i2));
        }
      }
    }
    rb += 32;
  }
}

// ------------------------------------- fused top-8 + fp64 rescore + STE update
__global__ void post_kernel(const float2* __restrict__ part,  // [32][NTOK] as float2 pairs
                            float* __restrict__ res,
                            const float* __restrict__ cb,     // layer codebook fp32
                            float* __restrict__ out,
                            _Float16* __restrict__ At,
                            float* __restrict__ idxf,
                            float* __restrict__ loss,
                            int first, int emit) {
  __shared__ float ls[4];
  const int lane = threadIdx.x & 63;
  const int rsub = threadIdx.x >> 6;
  const int row = blockIdx.x * 4 + rsub;

  // each lane holds one of 64 candidates: colTile = lane>>1, slot = lane&1
  const float2 p = part[((size_t)(lane >> 1) * NTOK + row) * 2 + (lane & 1)];
  float v = p.x;
  int   c = __float_as_int(p.y);

  int cand8[8];
  #pragma unroll
  for (int it = 0; it < 8; ++it) {
    float bv = v; int bi = c;
    #pragma unroll
    for (int m = 1; m < 64; m <<= 1) {
      const float ov = __shfl_xor(bv, m, 64);
      const int   oi = __shfl_xor(bi, m, 64);
      if (ov < bv || (ov == bv && oi < bi)) { bv = ov; bi = oi; }
    }
    cand8[it] = bi;
    if (c == bi) v = 3.0e38f;   // candidate cols are unique
  }

  const size_t base = (size_t)row * DIMD + lane * 4;
  const float4 r4 = *(const float4*)&res[base];

  double best = 1.0e300; int besti = KCB;
  #pragma unroll
  for (int it = 0; it < 8; ++it) {
    const int cc = cand8[it];
    const float4 q4 = *(const float4*)&cb[(size_t)cc * DIMD + lane * 4];
    const double t0 = (double)r4.x - (double)q4.x;
    const double t1 = (double)r4.y - (double)q4.y;
    const double t2 = (double)r4.z - (double)q4.z;
    const double t3 = (double)r4.w - (double)q4.w;
    double d = t0 * t0 + t1 * t1 + t2 * t2 + t3 * t3;
    #pragma unroll
    for (int m = 1; m < 64; m <<= 1) d += __shfl_xor(d, m, 64);
    if (d < best || (d == best && cc < besti)) { best = d; besti = cc; }
  }

  // ---- STE update with winner
  const float4 q4 = *(const float4*)&cb[(size_t)besti * DIMD + lane * 4];
  const float rr[4] = {r4.x, r4.y, r4.z, r4.w};
  const float qq[4] = {q4.x, q4.y, q4.z, q4.w};
  float nr[4], st[4];
  float s2 = 0.f;
  #pragma unroll
  for (int j = 0; j < 4; ++j) {
    const float stv = rr[j] + (qq[j] - rr[j]);   // STE value, ref rounding
    st[j] = stv;
    nr[j] = rr[j] - stv;
    const float dl = rr[j] - qq[j];
    s2 += dl * dl;
  }
  *(float4*)&res[base] = make_float4(nr[0], nr[1], nr[2], nr[3]);
  if (first) {
    *(float4*)&out[base] = make_float4(st[0], st[1], st[2], st[3]);
  } else {
    float4 o = *(const float4*)&out[base];
    o.x += st[0]; o.y += st[1]; o.z += st[2]; o.w += st[3];
    *(float4*)&out[base] = o;
  }
  if (emit) {
    half4 h;
    #pragma unroll
    for (int j = 0; j < 4; ++j) h[j] = (_Float16)nr[j];
    const int kc = lane >> 3, q = (lane >> 1) & 3, jo = (lane & 1) * 4;
    *(half4*)&At[(((size_t)(kc * (NTOK / 16) + (row >> 4))) * 64 + q * 16 + (row & 15)) * 8 + jo] = h;
  }
  if (lane == 0) idxf[row] = (float)besti;

  #pragma unroll
  for (int m = 1; m < 64; m <<= 1) s2 += __shfl_xor(s2, m, 64);
  if (lane == 0) ls[rsub] = s2;
  __syncthreads();
  if (threadIdx.x == 0) {
    const float tot = ls[0] + ls[1] + ls[2] + ls[3];
    atomicAdd(loss, tot * (1.0f / (float)((size_t)NTOK * DIMD)));
  }
}

// ---------------------------------------------------------------- launch
extern "C" void kernel_launch(void* const* d_in, const int* in_sizes, int n_in,
                              void* d_out, int out_size, void* d_ws, size_t ws_size,
                              hipStream_t stream) {
  const float* x   = (const float*)d_in[0];   // [8,4096,256]
  const float* cbs = (const float*)d_in[1];   // [4,4096,256]

  float* out    = (float*)d_out;
  float* idxf   = out + (size_t)NTOK * DIMD;
  float* losses = idxf + (size_t)NQ * NTOK;

  char* wsp = (char*)d_ws;
  float* res = (float*)wsp;                    wsp += (size_t)NTOK * DIMD * 4;      // 32 MB
  _Float16* At = (_Float16*)wsp;               wsp += (size_t)NTOK * DIMD * 2;      // 16 MB
  _Float16* Bt = (_Float16*)wsp;               wsp += (size_t)NQ * KCB * DIMD * 2;  //  8 MB
  float4* part = (float4*)wsp;                 wsp += (size_t)NTOK * 32 * 16;       // 16 MB
  float* cn = (float*)wsp;                     wsp += (size_t)NQ * KCB * 4;

  // out + idxf are fully overwritten each launch; only losses need zeroing.
  hipMemsetAsync(losses, 0, NQ * sizeof(float), stream);
  cb_prep_kernel<<<NQ * KCB / 8, 256, 0, stream>>>(cbs, Bt, cn);
  init_kernel<<<NTOK / 8, 256, 0, stream>>>(x, res, At);

  for (int q = 0; q < NQ; ++q) {
    const float* cb = cbs + (size_t)q * KCB * DIMD;
    argmin_kernel<<<256, 512, 0, stream>>>(At, Bt + (size_t)q * KCB * DIMD,
                                           cn + (size_t)q * KCB, part);
    post_kernel<<<NTOK / 4, 256, 0, stream>>>(
        (const float2*)part, res, cb, out, At, idxf + (size_t)q * NTOK,
        losses + q, q == 0 ? 1 : 0, q < NQ - 1 ? 1 : 0);
  }
}

// Round 5
// 851.659 us; speedup vs baseline: 1.8404x; 1.8404x over previous
//
#include <hip/hip_runtime.h>
#include <cstdint>

#define DIMD 256
#define KCB  4096
#define NQ   4
#define NTOK 32768   // 8 * 4096

typedef __attribute__((ext_vector_type(8))) _Float16 half8;
typedef __attribute__((ext_vector_type(4))) _Float16 half4;
typedef __attribute__((ext_vector_type(4))) float f32x4;

// ---------------------------------------------------------------- helpers
__device__ __forceinline__ void async16(const void* g, void* l) {
  __builtin_amdgcn_global_load_lds(
      (const __attribute__((address_space(1))) unsigned int*)g,
      (__attribute__((address_space(3))) unsigned int*)l, 16, 0, 0);
}

__device__ __forceinline__ f32x4 mfma16(half8 a, half8 b, f32x4 c) {
  return __builtin_amdgcn_mfma_f32_16x16x32_f16(a, b, c, 0, 0, 0);
}

// ---------------------------------------------------------------- prep
// A plane frag-linear for mfma_f32_16x16x32 A-operand:
// half index = ((kc*(NTOK/16) + rowBlock16)*64 + (q*16 + (row&15)))*8 + j
// where element (row, d): kc=d>>5, q=(d>>3)&3, j=d&7.
__global__ void init_kernel(const float* __restrict__ x,
                            float* __restrict__ res,
                            _Float16* __restrict__ At) {
  const int tid = threadIdx.x;
  const int n = blockIdx.x * 8 + (tid >> 5);
  const int t = tid & 31;
  const size_t base = (size_t)n * DIMD + t * 8;
  const float4 v0 = *(const float4*)&x[base];
  const float4 v1 = *(const float4*)&x[base + 4];
  *(float4*)&res[base]     = v0;
  *(float4*)&res[base + 4] = v1;
  const float f[8] = {v0.x, v0.y, v0.z, v0.w, v1.x, v1.y, v1.z, v1.w};
  half8 h;
  #pragma unroll
  for (int j = 0; j < 8; ++j) h[j] = (_Float16)f[j];
  const int kc = t >> 2, q = t & 3;
  *(half8*)&At[(((size_t)(kc * (NTOK / 16) + (n >> 4))) * 64 + q * 16 + (n & 15)) * 8] = h;
}

// B plane frag-linear, CHUNK-major so a 64-col chunk is one contiguous 32 KB:
// frag f = ((c>>6)*8 + kc)*4 + ((c>>4)&3); half = (f*64 + q*16 + (c&15))*8 + j.
// hcS[c] = 512 + 0.5*|cb_c|^2  (argmin key offset; d' = hcS - dot > 0 always
// since dist^2 = rn - 2dot + cn >= 0  =>  0.5cn - dot >= -0.5rn > -512).
__global__ void cb_prep_kernel(const float* __restrict__ cbs,
                               _Float16* __restrict__ Bt,
                               float* __restrict__ hcS) {
  const int tid = threadIdx.x;
  const int R = blockIdx.x * 8 + (tid >> 5);   // layer*4096 + code
  const int layer = R >> 12, c = R & 4095;
  const int t = tid & 31;
  const size_t base = (size_t)R * DIMD + t * 8;
  const float4 v0 = *(const float4*)&cbs[base];
  const float4 v1 = *(const float4*)&cbs[base + 4];
  const float f[8] = {v0.x, v0.y, v0.z, v0.w, v1.x, v1.y, v1.z, v1.w};
  half8 h;
  float s = 0.f;
  #pragma unroll
  for (int j = 0; j < 8; ++j) { h[j] = (_Float16)f[j]; s += f[j] * f[j]; }
  const int kc = t >> 2, q = t & 3;
  _Float16* BtL = Bt + (size_t)layer * KCB * DIMD;
  const int fr = ((c >> 6) * 8 + kc) * 4 + ((c >> 4) & 3);
  *(half8*)&BtL[((size_t)fr * 64 + q * 16 + (c & 15)) * 8] = h;
  #pragma unroll
  for (int off = 16; off > 0; off >>= 1) s += __shfl_down(s, off, 32);
  if (t == 0) hcS[R] = 512.0f + 0.5f * s;
}

// ---------------------------------------------------------------- argmin
// A resident in VGPRs (64 rows x 256 d per wave = 128 VGPRs, read from HBM
// once); B streamed through double-buffered LDS (16 chunks x 64 cols).
// Block: 8 waves = 512 rows x 1024 cols; grid = 64 rowgroups x 4 colQ.
__global__ __launch_bounds__(512, 2) void argmin_kernel(
    const _Float16* __restrict__ At,
    const _Float16* __restrict__ Bt,     // layer base (chunk-major frag-linear)
    const float* __restrict__ hcS,       // layer base
    uint2* __restrict__ part)            // [4][NTOK] best-2 col indices
{
  __shared__ _Float16 Bs[2][16384];      // 2 x 32 KB
  __shared__ float hcs[1024];

  const int tid = threadIdx.x;
  const int lane = tid & 63, w = tid >> 6;
  const int rg   = blockIdx.x & 63;      // stride-64 siblings share rows
  const int colQ = blockIdx.x >> 6;
  const int quad = lane >> 4, ln = lane & 15;

  // stage hcS quarter to LDS (1024 floats)
  *(float2*)&hcs[tid * 2] = *(const float2*)&hcS[colQ * 1024 + tid * 2];

  // stage B chunk 0 (32 KB = 32 frags; wave w stages frags w*4..w*4+3)
  const char* BtQ = (const char*)Bt + (size_t)colQ * 524288;
  #pragma unroll
  for (int r = 0; r < 4; ++r)
    async16(BtQ + (size_t)(w * 4 + r) * 1024 + lane * 16,
            (char*)&Bs[0][0] + (w * 4 + r) * 1024);

  // upfront A: 64 rows x 256 d in registers (32 x dwordx4)
  const int rb16 = rg * 32 + w * 4;
  half8 a[4][8];
  #pragma unroll
  for (int kc = 0; kc < 8; ++kc)
    #pragma unroll
    for (int rt = 0; rt < 4; ++rt)
      a[rt][kc] = *(const half8*)&At[(((size_t)(kc * (NTOK / 16) + rb16 + rt)) * 64 + lane) * 8];

  // best-2 keys per element (16 rows/lane): key = trunc6(as_uint(d')) | tile
  uint32_t u1[16], u2[16];
  #pragma unroll
  for (int s = 0; s < 16; ++s) { u1[s] = 0xFFFFFFFFu; u2[s] = 0xFFFFFFFFu; }

  __syncthreads();

  for (int cl = 0; cl < 16; ++cl) {
    const int cur = cl & 1;
    if (cl < 15) {   // stage next chunk into other buffer
      #pragma unroll
      for (int r = 0; r < 4; ++r)
        async16(BtQ + (size_t)(cl + 1) * 32768 + (w * 4 + r) * 1024 + lane * 16,
                (char*)&Bs[cur ^ 1][0] + (w * 4 + r) * 1024);
    }
    #pragma unroll
    for (int tsub = 0; tsub < 4; ++tsub) {
      const int tl = cl * 4 + tsub;      // tile 0..63 within quarter
      half8 b[8];
      #pragma unroll
      for (int kc = 0; kc < 8; ++kc)
        b[kc] = *(const half8*)&Bs[cur][(kc * 4 + tsub) * 512 + lane * 8];
      f32x4 acc[4];
      #pragma unroll
      for (int rt = 0; rt < 4; ++rt) acc[rt] = (f32x4){0.f, 0.f, 0.f, 0.f};
      #pragma unroll
      for (int kc = 0; kc < 8; ++kc) {
        acc[0] = mfma16(a[0][kc], b[kc], acc[0]);
        acc[1] = mfma16(a[1][kc], b[kc], acc[1]);
        acc[2] = mfma16(a[2][kc], b[kc], acc[2]);
        acc[3] = mfma16(a[3][kc], b[kc], acc[3]);
      }
      const float hcv = hcs[tl * 16 + ln];
      #pragma unroll
      for (int rt = 0; rt < 4; ++rt)
        #pragma unroll
        for (int reg = 0; reg < 4; ++reg) {
          const uint32_t k =
              (__float_as_uint(hcv - acc[rt][reg]) & 0xFFFFFFC0u) | (uint32_t)tl;
          const int s = rt * 4 + reg;
          const uint32_t mx = u1[s] > k ? u1[s] : k;
          u1[s] = u1[s] < k ? u1[s] : k;
          u2[s] = u2[s] < mx ? u2[s] : mx;
        }
    }
    __syncthreads();
  }

  // flush: reconstruct cols, merge best-2 across the 16 ln lanes, write part
  #pragma unroll
  for (int s = 0; s < 16; ++s) {
    uint32_t k1 = u1[s], k2 = u2[s];
    int c1 = colQ * 1024 + (int)(k1 & 63u) * 16 + ln;
    int c2 = colQ * 1024 + (int)(k2 & 63u) * 16 + ln;
    #pragma unroll
    for (int m = 1; m <= 8; m <<= 1) {
      const uint32_t o1 = (uint32_t)__shfl_xor((int)k1, m, 64);
      const int      oc1 = __shfl_xor(c1, m, 64);
      const uint32_t o2 = (uint32_t)__shfl_xor((int)k2, m, 64);
      const int      oc2 = __shfl_xor(c2, m, 64);
      const bool t1 = k1 <= o1;
      const uint32_t am = t1 ? o1 : k1; const int amc = t1 ? oc1 : c1;
      k1 = t1 ? k1 : o1;                c1 = t1 ? c1 : oc1;
      const bool t2 = k2 <= o2;
      const uint32_t bm = t2 ? k2 : o2; const int bmc = t2 ? c2 : oc2;
      const bool t3 = am <= bm;
      k2 = t3 ? am : bm;                c2 = t3 ? amc : bmc;
    }
    if (ln == 0) {
      const int rt = s >> 2, reg = s & 3;
      const int row = rg * 512 + w * 64 + rt * 16 + quad * 4 + reg;
      part[(size_t)colQ * NTOK + row] = make_uint2((uint32_t)c1, (uint32_t)c2);
    }
  }
}

// ------------------------- fused fp64 rescore (8 cands) + STE update + loss
__global__ void post_kernel(const uint2* __restrict__ part,
                            float* __restrict__ res,
                            const float* __restrict__ cb,   // layer fp32
                            float* __restrict__ out,
                            _Float16* __restrict__ At,
                            float* __restrict__ idxf,
                            float* __restrict__ loss,
                            int first, int emit) {
  __shared__ float ls[4];
  const int lane = threadIdx.x & 63;
  const int rsub = threadIdx.x >> 6;
  const int row = blockIdx.x * 4 + rsub;

  int cand[8];
  #pragma unroll
  for (int cq = 0; cq < 4; ++cq) {
    const uint2 p = part[(size_t)cq * NTOK + row];
    cand[cq * 2] = (int)p.x; cand[cq * 2 + 1] = (int)p.y;
  }
  // lane-parallel rescore: cand id = lane>>3, dim group = (lane&7)*32
  const int cd = lane >> 3, dg = lane & 7;
  const int myc = cand[cd];
  const float* rrow = res + (size_t)row * DIMD;
  const float* qrow = cb + (size_t)myc * DIMD;
  double d = 0.0;
  #pragma unroll
  for (int k = 0; k < 8; ++k) {
    const int dd = dg * 32 + k * 4;
    const float4 rv = *(const float4*)&rrow[dd];
    const float4 qv = *(const float4*)&qrow[dd];
    const double t0 = (double)rv.x - (double)qv.x;
    const double t1 = (double)rv.y - (double)qv.y;
    const double t2 = (double)rv.z - (double)qv.z;
    const double t3 = (double)rv.w - (double)qv.w;
    d += t0 * t0 + t1 * t1 + t2 * t2 + t3 * t3;
  }
  #pragma unroll
  for (int m = 1; m <= 4; m <<= 1) d += __shfl_xor(d, m, 64);
  double bd = d; int bc = myc;
  #pragma unroll
  for (int m = 8; m <= 32; m <<= 1) {
    const double od = __shfl_xor(bd, m, 64);
    const int    oc = __shfl_xor(bc, m, 64);
    if (od < bd || (od == bd && oc < bc)) { bd = od; bc = oc; }
  }
  const int win = bc;

  // STE update (reference rounding)
  const size_t base = (size_t)row * DIMD + lane * 4;
  const float4 r4 = *(const float4*)&res[base];
  const float4 q4 = *(const float4*)&cb[(size_t)win * DIMD + lane * 4];
  const float rr[4] = {r4.x, r4.y, r4.z, r4.w};
  const float qq[4] = {q4.x, q4.y, q4.z, q4.w};
  float nr[4], st[4];
  float s2 = 0.f;
  #pragma unroll
  for (int j = 0; j < 4; ++j) {
    const float stv = rr[j] + (qq[j] - rr[j]);
    st[j] = stv;
    nr[j] = rr[j] - stv;
    const float dl = rr[j] - qq[j];
    s2 += dl * dl;
  }
  *(float4*)&res[base] = make_float4(nr[0], nr[1], nr[2], nr[3]);
  if (first) {
    *(float4*)&out[base] = make_float4(st[0], st[1], st[2], st[3]);
  } else {
    float4 o = *(const float4*)&out[base];
    o.x += st[0]; o.y += st[1]; o.z += st[2]; o.w += st[3];
    *(float4*)&out[base] = o;
  }
  if (emit) {
    half4 h;
    #pragma unroll
    for (int j = 0; j < 4; ++j) h[j] = (_Float16)nr[j];
    const int kc = lane >> 3, q = (lane >> 1) & 3, jo = (lane & 1) * 4;
    *(half4*)&At[(((size_t)(kc * (NTOK / 16) + (row >> 4))) * 64 + q * 16 + (row & 15)) * 8 + jo] = h;
  }
  if (lane == 0) idxf[row] = (float)win;

  #pragma unroll
  for (int m = 1; m < 64; m <<= 1) s2 += __shfl_xor(s2, m, 64);
  if (lane == 0) ls[rsub] = s2;
  __syncthreads();
  if (threadIdx.x == 0) {
    const float tot = ls[0] + ls[1] + ls[2] + ls[3];
    atomicAdd(loss, tot * (1.0f / (float)((size_t)NTOK * DIMD)));
  }
}

// ---------------------------------------------------------------- launch
extern "C" void kernel_launch(void* const* d_in, const int* in_sizes, int n_in,
                              void* d_out, int out_size, void* d_ws, size_t ws_size,
                              hipStream_t stream) {
  const float* x   = (const float*)d_in[0];   // [8,4096,256]
  const float* cbs = (const float*)d_in[1];   // [4,4096,256]

  float* out    = (float*)d_out;
  float* idxf   = out + (size_t)NTOK * DIMD;
  float* losses = idxf + (size_t)NQ * NTOK;

  char* wsp = (char*)d_ws;
  float* res = (float*)wsp;                    wsp += (size_t)NTOK * DIMD * 4;      // 32 MB
  _Float16* At = (_Float16*)wsp;               wsp += (size_t)NTOK * DIMD * 2;      // 16 MB
  _Float16* Bt = (_Float16*)wsp;               wsp += (size_t)NQ * KCB * DIMD * 2;  //  8 MB
  float* hcS = (float*)wsp;                    wsp += (size_t)NQ * KCB * 4;
  uint2* part = (uint2*)wsp;                   wsp += (size_t)NTOK * 4 * 8;         // 1 MB

  hipMemsetAsync(losses, 0, NQ * sizeof(float), stream);
  cb_prep_kernel<<<NQ * KCB / 8, 256, 0, stream>>>(cbs, Bt, hcS);
  init_kernel<<<NTOK / 8, 256, 0, stream>>>(x, res, At);

  for (int q = 0; q < NQ; ++q) {
    const float* cb = cbs + (size_t)q * KCB * DIMD;
    argmin_kernel<<<256, 512, 0, stream>>>(At, Bt + (size_t)q * KCB * DIMD,
                                           hcS + (size_t)q * KCB, part);
    post_kernel<<<NTOK / 4, 256, 0, stream>>>(
        part, res, cb, out, At, idxf + (size_t)q * NTOK,
        losses + q, q == 0 ? 1 : 0, q < NQ - 1 ? 1 : 0);
  }
}

// Round 6
// 646.125 us; speedup vs baseline: 2.4258x; 1.3181x over previous
//
#include <hip/hip_runtime.h>
#include <cstdint>

#define DIMD 256
#define KCB  4096
#define NQ   4
#define NTOK 32768   // 8 * 4096

typedef __attribute__((ext_vector_type(8))) _Float16 half8;
typedef __attribute__((ext_vector_type(4))) _Float16 half4;
typedef __attribute__((ext_vector_type(4))) float f32x4;

// ---------------------------------------------------------------- helpers
__device__ __forceinline__ void async16(const void* g, void* l) {
  __builtin_amdgcn_global_load_lds(
      (const __attribute__((address_space(1))) unsigned int*)g,
      (__attribute__((address_space(3))) unsigned int*)l, 16, 0, 0);
}

__device__ __forceinline__ f32x4 mfma16(half8 a, half8 b, f32x4 c) {
  return __builtin_amdgcn_mfma_f32_16x16x32_f16(a, b, c, 0, 0, 0);
}

// ---------------------------------------------------------------- prep
// A plane frag-linear for mfma_f32_16x16x32 A-operand:
// half index = ((kc*(NTOK/16) + rowBlock16)*64 + (q*16 + (row&15)))*8 + j
// where element (row, d): kc=d>>5, q=(d>>3)&3, j=d&7.
__global__ void init_kernel(const float* __restrict__ x,
                            _Float16* __restrict__ At) {
  const int tid = threadIdx.x;
  const int n = blockIdx.x * 8 + (tid >> 5);
  const int t = tid & 31;
  const size_t base = (size_t)n * DIMD + t * 8;
  const float4 v0 = *(const float4*)&x[base];
  const float4 v1 = *(const float4*)&x[base + 4];
  const float f[8] = {v0.x, v0.y, v0.z, v0.w, v1.x, v1.y, v1.z, v1.w};
  half8 h;
  #pragma unroll
  for (int j = 0; j < 8; ++j) h[j] = (_Float16)f[j];
  const int kc = t >> 2, q = t & 3;
  *(half8*)&At[(((size_t)(kc * (NTOK / 16) + (n >> 4))) * 64 + q * 16 + (n & 15)) * 8] = h;
}

// B plane frag-linear, CHUNK-major so a 64-col chunk is one contiguous 32 KB:
// frag f = ((c>>6)*8 + kc)*4 + ((c>>4)&3); half = (f*64 + q*16 + (c&15))*8 + j.
// hcS[c] = 512 + 0.5*|cb_c|^2  (argmin key offset; d' = hcS - dot > 0 always).
__global__ void cb_prep_kernel(const float* __restrict__ cbs,
                               _Float16* __restrict__ Bt,
                               float* __restrict__ hcS) {
  const int tid = threadIdx.x;
  const int R = blockIdx.x * 8 + (tid >> 5);   // layer*4096 + code
  const int layer = R >> 12, c = R & 4095;
  const int t = tid & 31;
  const size_t base = (size_t)R * DIMD + t * 8;
  const float4 v0 = *(const float4*)&cbs[base];
  const float4 v1 = *(const float4*)&cbs[base + 4];
  const float f[8] = {v0.x, v0.y, v0.z, v0.w, v1.x, v1.y, v1.z, v1.w};
  half8 h;
  float s = 0.f;
  #pragma unroll
  for (int j = 0; j < 8; ++j) { h[j] = (_Float16)f[j]; s += f[j] * f[j]; }
  const int kc = t >> 2, q = t & 3;
  _Float16* BtL = Bt + (size_t)layer * KCB * DIMD;
  const int fr = ((c >> 6) * 8 + kc) * 4 + ((c >> 4) & 3);
  *(half8*)&BtL[((size_t)fr * 64 + q * 16 + (c & 15)) * 8] = h;
  #pragma unroll
  for (int off = 16; off > 0; off >>= 1) s += __shfl_down(s, off, 32);
  if (t == 0) hcS[R] = 512.0f + 0.5f * s;
}

// ---------------------------------------------------------------- argmin
// A resident in VGPRs (64 rows x 256 d per wave, read from HBM once); B
// streamed through double-buffered LDS. Block: 4 waves = 256 rows x 1024
// cols; grid = 128 rowgroups x 4 colQ = 512 blocks -> 2 blocks/CU so the
// per-chunk barrier drains of one block hide under the other's compute.
__global__ __launch_bounds__(256, 2) void argmin_kernel(
    const _Float16* __restrict__ At,
    const _Float16* __restrict__ Bt,     // layer base (chunk-major frag-linear)
    const float* __restrict__ hcS,       // layer base
    uint2* __restrict__ part)            // [NTOK][4] best-2 col indices
{
  __shared__ _Float16 Bs[2][16384];      // 2 x 32 KB
  __shared__ float hcs[1024];

  const int tid = threadIdx.x;
  const int lane = tid & 63, w = tid >> 6;   // 4 waves
  const int rg   = blockIdx.x & 127;         // stride-128 siblings share rows
  const int colQ = blockIdx.x >> 7;
  const int quad = lane >> 4, ln = lane & 15;

  // stage hcS quarter to LDS (1024 floats)
  *(float4*)&hcs[tid * 4] = *(const float4*)&hcS[colQ * 1024 + tid * 4];

  // stage B chunk 0 (32 KB = 32 frags; wave w stages frags w*8..w*8+7)
  const char* BtQ = (const char*)Bt + (size_t)colQ * 524288;
  #pragma unroll
  for (int r = 0; r < 8; ++r)
    async16(BtQ + (size_t)(w * 8 + r) * 1024 + lane * 16,
            (char*)&Bs[0][0] + (w * 8 + r) * 1024);

  // upfront A: 64 rows x 256 d in registers (32 x dwordx4)
  const int rb16 = rg * 16 + w * 4;
  half8 a[4][8];
  #pragma unroll
  for (int kc = 0; kc < 8; ++kc)
    #pragma unroll
    for (int rt = 0; rt < 4; ++rt)
      a[rt][kc] = *(const half8*)&At[(((size_t)(kc * (NTOK / 16) + rb16 + rt)) * 64 + lane) * 8];

  // best-2 keys per element (16 rows/lane): key = trunc6(as_uint(d')) | tile
  uint32_t u1[16], u2[16];
  #pragma unroll
  for (int s = 0; s < 16; ++s) { u1[s] = 0xFFFFFFFFu; u2[s] = 0xFFFFFFFFu; }

  __syncthreads();

  for (int cl = 0; cl < 16; ++cl) {
    const int cur = cl & 1;
    if (cl < 15) {   // stage next chunk into other buffer
      #pragma unroll
      for (int r = 0; r < 8; ++r)
        async16(BtQ + (size_t)(cl + 1) * 32768 + (w * 8 + r) * 1024 + lane * 16,
                (char*)&Bs[cur ^ 1][0] + (w * 8 + r) * 1024);
    }
    #pragma unroll
    for (int tsub = 0; tsub < 4; ++tsub) {
      const int tl = cl * 4 + tsub;      // tile 0..63 within quarter
      half8 b[8];
      #pragma unroll
      for (int kc = 0; kc < 8; ++kc)
        b[kc] = *(const half8*)&Bs[cur][(kc * 4 + tsub) * 512 + lane * 8];
      f32x4 acc[4];
      #pragma unroll
      for (int rt = 0; rt < 4; ++rt) acc[rt] = (f32x4){0.f, 0.f, 0.f, 0.f};
      #pragma unroll
      for (int kc = 0; kc < 8; ++kc) {
        acc[0] = mfma16(a[0][kc], b[kc], acc[0]);
        acc[1] = mfma16(a[1][kc], b[kc], acc[1]);
        acc[2] = mfma16(a[2][kc], b[kc], acc[2]);
        acc[3] = mfma16(a[3][kc], b[kc], acc[3]);
      }
      const float hcv = hcs[tl * 16 + ln];
      #pragma unroll
      for (int rt = 0; rt < 4; ++rt)
        #pragma unroll
        for (int reg = 0; reg < 4; ++reg) {
          const uint32_t k =
              (__float_as_uint(hcv - acc[rt][reg]) & 0xFFFFFFC0u) | (uint32_t)tl;
          const int s = rt * 4 + reg;
          const uint32_t mx = u1[s] > k ? u1[s] : k;
          u1[s] = u1[s] < k ? u1[s] : k;
          u2[s] = u2[s] < mx ? u2[s] : mx;
        }
    }
    __syncthreads();
  }

  // flush: reconstruct cols, merge best-2 across the 16 ln lanes, write part
  #pragma unroll
  for (int s = 0; s < 16; ++s) {
    uint32_t k1 = u1[s], k2 = u2[s];
    int c1 = colQ * 1024 + (int)(k1 & 63u) * 16 + ln;
    int c2 = colQ * 1024 + (int)(k2 & 63u) * 16 + ln;
    #pragma unroll
    for (int m = 1; m <= 8; m <<= 1) {
      const uint32_t o1 = (uint32_t)__shfl_xor((int)k1, m, 64);
      const int      oc1 = __shfl_xor(c1, m, 64);
      const uint32_t o2 = (uint32_t)__shfl_xor((int)k2, m, 64);
      const int      oc2 = __shfl_xor(c2, m, 64);
      const bool t1 = k1 <= o1;
      const uint32_t am = t1 ? o1 : k1; const int amc = t1 ? oc1 : c1;
      k1 = t1 ? k1 : o1;                c1 = t1 ? c1 : oc1;
      const bool t2 = k2 <= o2;
      const uint32_t bm = t2 ? k2 : o2; const int bmc = t2 ? c2 : oc2;
      const bool t3 = am <= bm;
      k2 = t3 ? am : bm;                c2 = t3 ? amc : bmc;
    }
    if (ln == 0) {
      const int rt = s >> 2, reg = s & 3;
      const int row = rg * 256 + w * 64 + rt * 16 + quad * 4 + reg;
      part[(size_t)row * 4 + colQ] = make_uint2((uint32_t)c1, (uint32_t)c2);
    }
  }
}

// ------------------------- fused fp64 rescore (8 cands) + STE update + loss
// Residual identity: res_final = x - sum(stv) exactly, so `out` is written
// only at the last layer as out = x - nr (fp diff vs ref sum order ~2e-6).
__global__ void post_kernel(const uint2* __restrict__ part,
                            const float* __restrict__ rsrc,  // x (q=0) or res
                            float* __restrict__ rdst,        // res
                            const float* __restrict__ xin,   // x (last layer)
                            const float* __restrict__ cb,    // layer fp32
                            float* __restrict__ out,
                            _Float16* __restrict__ At,
                            float* __restrict__ idxf,
                            float* __restrict__ lossP,       // 256 slots
                            int writeRes, int emit, int writeOut) {
  __shared__ float ls[4];
  const int lane = threadIdx.x & 63;
  const int rsub = threadIdx.x >> 6;
  const int row = blockIdx.x * 4 + rsub;

  const uint4 pa = *(const uint4*)&part[(size_t)row * 4];
  const uint4 pb = *(const uint4*)&part[(size_t)row * 4 + 2];
  const int cand[8] = {(int)pa.x, (int)pa.y, (int)pa.z, (int)pa.w,
                       (int)pb.x, (int)pb.y, (int)pb.z, (int)pb.w};

  // lane-parallel rescore: cand id = lane>>3, dim group = (lane&7)*32
  const int cd = lane >> 3, dg = lane & 7;
  const int myc = cand[cd];
  const float* rrow = rsrc + (size_t)row * DIMD;
  const float* qrow = cb + (size_t)myc * DIMD;
  double d = 0.0;
  #pragma unroll
  for (int k = 0; k < 8; ++k) {
    const int dd = dg * 32 + k * 4;
    const float4 rv = *(const float4*)&rrow[dd];
    const float4 qv = *(const float4*)&qrow[dd];
    const double t0 = (double)rv.x - (double)qv.x;
    const double t1 = (double)rv.y - (double)qv.y;
    const double t2 = (double)rv.z - (double)qv.z;
    const double t3 = (double)rv.w - (double)qv.w;
    d += t0 * t0 + t1 * t1 + t2 * t2 + t3 * t3;
  }
  #pragma unroll
  for (int m = 1; m <= 4; m <<= 1) d += __shfl_xor(d, m, 64);
  double bd = d; int bc = myc;
  #pragma unroll
  for (int m = 8; m <= 32; m <<= 1) {
    const double od = __shfl_xor(bd, m, 64);
    const int    oc = __shfl_xor(bc, m, 64);
    if (od < bd || (od == bd && oc < bc)) { bd = od; bc = oc; }
  }
  const int win = bc;

  // STE update (reference rounding)
  const size_t base = (size_t)row * DIMD + lane * 4;
  const float4 r4 = *(const float4*)&rsrc[base];
  const float4 q4 = *(const float4*)&cb[(size_t)win * DIMD + lane * 4];
  const float rr[4] = {r4.x, r4.y, r4.z, r4.w};
  const float qq[4] = {q4.x, q4.y, q4.z, q4.w};
  float nr[4];
  float s2 = 0.f;
  #pragma unroll
  for (int j = 0; j < 4; ++j) {
    const float stv = rr[j] + (qq[j] - rr[j]);
    nr[j] = rr[j] - stv;
    const float dl = rr[j] - qq[j];
    s2 += dl * dl;
  }
  if (writeRes)
    *(float4*)&rdst[base] = make_float4(nr[0], nr[1], nr[2], nr[3]);
  if (writeOut) {
    const float4 xv = *(const float4*)&xin[base];
    *(float4*)&out[base] =
        make_float4(xv.x - nr[0], xv.y - nr[1], xv.z - nr[2], xv.w - nr[3]);
  }
  if (emit) {
    half4 h;
    #pragma unroll
    for (int j = 0; j < 4; ++j) h[j] = (_Float16)nr[j];
    const int kc = lane >> 3, q = (lane >> 1) & 3, jo = (lane & 1) * 4;
    *(half4*)&At[(((size_t)(kc * (NTOK / 16) + (row >> 4))) * 64 + q * 16 + (row & 15)) * 8 + jo] = h;
  }
  if (lane == 0) idxf[row] = (float)win;

  #pragma unroll
  for (int m = 1; m < 64; m <<= 1) s2 += __shfl_xor(s2, m, 64);
  if (lane == 0) ls[rsub] = s2;
  __syncthreads();
  if (threadIdx.x == 0) {
    const float tot = ls[0] + ls[1] + ls[2] + ls[3];
    atomicAdd(&lossP[blockIdx.x & 255],
              tot * (1.0f / (float)((size_t)NTOK * DIMD)));
  }
}

// sum 4 x 256 loss partials -> losses[4]
__global__ void finalize_kernel(const float* __restrict__ lossP,
                                float* __restrict__ losses) {
  const int w = threadIdx.x >> 6, lane = threadIdx.x & 63;
  float s = lossP[w * 256 + lane] + lossP[w * 256 + 64 + lane] +
            lossP[w * 256 + 128 + lane] + lossP[w * 256 + 192 + lane];
  #pragma unroll
  for (int m = 1; m < 64; m <<= 1) s += __shfl_xor(s, m, 64);
  if (lane == 0) losses[w] = s;
}

// ---------------------------------------------------------------- launch
extern "C" void kernel_launch(void* const* d_in, const int* in_sizes, int n_in,
                              void* d_out, int out_size, void* d_ws, size_t ws_size,
                              hipStream_t stream) {
  const float* x   = (const float*)d_in[0];   // [8,4096,256]
  const float* cbs = (const float*)d_in[1];   // [4,4096,256]

  float* out    = (float*)d_out;
  float* idxf   = out + (size_t)NTOK * DIMD;
  float* losses = idxf + (size_t)NQ * NTOK;

  char* wsp = (char*)d_ws;
  float* res = (float*)wsp;                    wsp += (size_t)NTOK * DIMD * 4;      // 32 MB
  _Float16* At = (_Float16*)wsp;               wsp += (size_t)NTOK * DIMD * 2;      // 16 MB
  _Float16* Bt = (_Float16*)wsp;               wsp += (size_t)NQ * KCB * DIMD * 2;  //  8 MB
  float* hcS = (float*)wsp;                    wsp += (size_t)NQ * KCB * 4;
  uint2* part = (uint2*)wsp;                   wsp += (size_t)NTOK * 4 * 8;
  float* lossP = (float*)wsp;                  wsp += (size_t)NQ * 256 * 4;

  hipMemsetAsync(lossP, 0, NQ * 256 * sizeof(float), stream);
  cb_prep_kernel<<<NQ * KCB / 8, 256, 0, stream>>>(cbs, Bt, hcS);
  init_kernel<<<NTOK / 8, 256, 0, stream>>>(x, At);

  for (int q = 0; q < NQ; ++q) {
    const float* cb = cbs + (size_t)q * KCB * DIMD;
    argmin_kernel<<<512, 256, 0, stream>>>(At, Bt + (size_t)q * KCB * DIMD,
                                           hcS + (size_t)q * KCB, part);
    const int last = (q == NQ - 1);
    post_kernel<<<NTOK / 4, 256, 0, stream>>>(
        part, q == 0 ? x : res, res, x, cb, out, At,
        idxf + (size_t)q * NTOK, lossP + (size_t)q * 256,
        /*writeRes=*/!last, /*emit=*/!last, /*writeOut=*/last);
  }
  finalize_kernel<<<1, 256, 0, stream>>>(lossP, losses);
}